// Round 10
// baseline (222.952 us; speedup 1.0000x reference)
//
#include <hip/hip_runtime.h>

// VQSpeaker: obs[32,2048,128] -> 3-layer MLP -> x[65536,64] -> VQ argmin over
// codebook[2048,64] -> (msg = codebook[idx], idx, cmt_loss).
//
// Round 18: BARRIER-FREE scan via wave-private LDS staging + counted vmcnt.
//   R17 counters: 40% VALU / 60% stall; barrier-phase lockstep + unpipelined
//   per-tile ds->MFMA->screen chains are the stall. Now each wave stages its
//   OWN 2KB/tile stream (global_load_lds, 3-buffer ring, depth-2 prefetch)
//   and orders it with explicit `s_waitcnt vmcnt(4)` + sched_barrier(0)
//   (wave-local T4; no cross-wave visibility needed -> ZERO barriers across
//   the 128-tile scan; waves fully self-paced). e2 staged to LDS once so the
//   loop has exactly 2 vmem ops/iter (exact vmcnt accounting).
//   Blocks: 256 thr / 4 waves / 64 pts; LDS ~53 KB -> 3 blocks/CU.
//   Screen operands, candidate semantics, rescore, loss: bit-identical.
//
// d_out layout (float32): msg[4194304] | idx[65536] (as float) | loss[1]
// d_ws: e2[2048] | cbh fp16 256KB | w1h/w1l 16KB ea | w2h/w2l/w3h/w3l 8KB ea

#define NPTS    65536
#define IN_DIM  128
#define HID     64
#define OUT_DIM 64
#define CB_N    2048
#define MSG_ELEMS (NPTS * OUT_DIM)
#define LOSS_SCALE (1.0f / 4194304.0f)
#define MARG 0.5f          // R3-proven screening margin
#define CAND_CAP 512       // 8 per point (64 pts)
#define BPTS 64            // points per block (4 waves x 16)
#define NTHR 256

typedef __attribute__((ext_vector_type(8))) short short8;
typedef _Float16 half8 __attribute__((ext_vector_type(8)));
typedef __attribute__((ext_vector_type(4))) float f32x4;
typedef unsigned int u32;
typedef unsigned long long u64;

// async global->LDS, 16B/lane: LDS dest = wave-uniform base + lane*16
__device__ __forceinline__ void gld16(void* lds_base, const void* gsrc) {
    __builtin_amdgcn_global_load_lds(
        (const __attribute__((address_space(1))) u32*)gsrc,
        (__attribute__((address_space(3))) u32*)lds_base, 16, 0, 0);
}

// ---- merged prep, 80 blocks: 0-63 prep_cb, 64-71 prep_w, 72-79 e2(+loss) --
__global__ __launch_bounds__(256) void prep_all(
    const float* __restrict__ cb,
    const float* __restrict__ W1, const float* __restrict__ W2,
    const float* __restrict__ W3,
    float* __restrict__ e2,
    _Float16* __restrict__ cbh,
    _Float16* __restrict__ w1h, _Float16* __restrict__ w1l,
    _Float16* __restrict__ w2h, _Float16* __restrict__ w2l,
    _Float16* __restrict__ w3h, _Float16* __restrict__ w3l,
    float* __restrict__ loss)
{
    const int b = blockIdx.x, tid = threadIdx.x;
    if (b < 64) {
        // ---- prep_cb: one (code n, half h, quad) per thread ----
        const int id = b * 256 + tid;               // 0..16383
        const int n = id >> 3, h = (id >> 2) & 1, quad = id & 3;
        const int t = n >> 4, l15 = n & 15;
        const float* src = cb + (long)n * OUT_DIM + h * 32 + quad * 8;
        half8 hi;
        #pragma unroll
        for (int j = 0; j < 8; ++j)
            hi[j] = (_Float16)src[j];
        const long dst = ((long)(t * 2 + h) * 64 + quad * 16 + l15) * 8;
        *(half8*)(cbh + dst) = hi;
    } else if (b < 72) {
        // ---- prep_w: W1/W2/W3 -> MFMA B-frag order, fp16 hi/lo split ----
        const int id = (b - 64) * 256 + tid;        // 0..2047
        const int lane = id & 63;
        const int m = lane & 15, quad = lane >> 4;
        const float* W; _Float16 *dh, *dl; int frag;
        if (id < 1024)      { W = W1; dh = w1h; dl = w1l; frag = id >> 6; }
        else if (id < 1536) { W = W2; dh = w2h; dl = w2l; frag = (id - 1024) >> 6; }
        else                { W = W3; dh = w3h; dl = w3l; frag = (id - 1536) >> 6; }
        const int kc = frag >> 2, nt = frag & 3;
        half8 hi, lo;
        #pragma unroll
        for (int j = 0; j < 8; ++j) {
            const float v = W[(long)(kc * 32 + quad * 8 + j) * 64 + nt * 16 + m];
            hi[j] = (_Float16)v;
            lo[j] = (_Float16)(v - (float)hi[j]);
        }
        const long dst = (long)(frag * 64 + lane) * 8;
        *(half8*)(dh + dst) = hi;
        *(half8*)(dl + dst) = lo;
    } else {
        // ---- e2 + zero_loss ----
        if (b == 72 && tid == 0) *loss = 0.0f;
        const int c = (b - 72) * 256 + tid;
        const float4* row = (const float4*)(cb + (long)c * OUT_DIM);
        float s = 0.0f;
        #pragma unroll
        for (int mq = 0; mq < 16; ++mq) {
            const float4 v = row[mq];
            s += v.x * v.x + v.y * v.y + v.z * v.z + v.w * v.w;
        }
        e2[c] = s;
    }
}

#define MFMA16(A, B, C) __builtin_amdgcn_mfma_f32_16x16x32_f16(A, B, C, 0, 0, 0)

__device__ __forceinline__ void split16(const float* xs, half8& h, half8& l) {
    #pragma unroll
    for (int j = 0; j < 8; ++j) {
        h[j] = (_Float16)xs[j];
        l[j] = (_Float16)(xs[j] - (float)h[j]);
    }
}

// packed rescore key: (total-order fp32 dist << 32) | code.
__device__ __forceinline__ u64 packkey(float d, int n) {
    u32 ub = __float_as_uint(d);
    ub = (ub & 0x80000000u) ? ~ub : (ub | 0x80000000u);
    return ((u64)ub << 32) | (u32)n;
}

// exact fp32 distance (R2/R3-proven pairing); xr is LDS, cbrow global.
__device__ __forceinline__ float exdist(
    const float* xr, const float* __restrict__ cbrow, float e2v)
{
    const float4* xp = (const float4*)xr;
    const float4* cp = (const float4*)cbrow;
    float a0 = 0.0f, a1 = 0.0f;
    #pragma unroll
    for (int mq = 0; mq < 16; ++mq) {
        const float4 xv = xp[mq], cv = cp[mq];
        a0 = fmaf(xv.x, cv.x, a0); a1 = fmaf(xv.y, cv.y, a1);
        a0 = fmaf(xv.z, cv.z, a0); a1 = fmaf(xv.w, cv.w, a1);
    }
    return fmaf(-2.0f, a0 + a1, e2v);
}

// ---------------- FUSED: MLP + VQ, barrier-free self-paced scan ------------
__global__ __launch_bounds__(NTHR, 4) void fused_mlp_vq(
    const float* __restrict__ obs,
    const float* __restrict__ b1, const float* __restrict__ b2,
    const float* __restrict__ b3,
    const _Float16* __restrict__ w1h, const _Float16* __restrict__ w1l,
    const _Float16* __restrict__ w2h, const _Float16* __restrict__ w2l,
    const _Float16* __restrict__ w3h, const _Float16* __restrict__ w3l,
    const float* __restrict__ cb,
    const _Float16* __restrict__ cbhp,
    const float* __restrict__ e2,
    float* __restrict__ msg,        // out only: quantize
    float* __restrict__ idx_out,
    float* __restrict__ loss_out)
{
    __shared__ float hbuf[BPTS * 68];            // 17.4 KB: mlp scratch then x
    __shared__ float e2s[CB_N];                  // 8 KB
    __shared__ __align__(16) char stg[4][3][2048];  // 24 KB wave-private rings
    __shared__ int   cand_pc[CAND_CAP];          // 2 KB: (p_local<<16) | code
    __shared__ u64   keys[BPTS];
    __shared__ int   win_sh[BPTS];
    __shared__ int   idx_sh[BPTS];
    __shared__ float wred[NTHR / 64];
    __shared__ int   cand_cnt;

    const int t = threadIdx.x, lane = t & 63, w = t >> 6;
    const int m = lane & 15, quad = lane >> 4;
    const long base = (long)blockIdx.x * BPTS;
    const int row0 = w * 16 + quad * 4;
    const int arow_l = w * 16 + m;

    if (t == 0) cand_cnt = 0;
    if (t < BPTS) keys[t] = ~0ULL;
    // e2 -> LDS (2048 floats, 2 float4/thread, coalesced)
    ((float4*)e2s)[t * 2]     = ((const float4*)e2)[t * 2];
    ((float4*)e2s)[t * 2 + 1] = ((const float4*)e2)[t * 2 + 1];

    // ================= MLP phase (R13-verbatim, wave-local, 4 waves) ========
    {
        float bb1[4], bb2[4], bb3[4];
        #pragma unroll
        for (int nt = 0; nt < 4; ++nt) {
            bb1[nt] = b1[nt * 16 + m];
            bb2[nt] = b2[nt * 16 + m];
            bb3[nt] = b3[nt * 16 + m];
        }

        const float* arow = obs + (base + w * 16 + m) * IN_DIM;
        half8 a1h[4], a1l[4];
        #pragma unroll
        for (int kc = 0; kc < 4; ++kc) {
            const float4 va = *(const float4*)(arow + kc * 32 + quad * 8);
            const float4 vb = *(const float4*)(arow + kc * 32 + quad * 8 + 4);
            const float xs[8] = {va.x, va.y, va.z, va.w, vb.x, vb.y, vb.z, vb.w};
            split16(xs, a1h[kc], a1l[kc]);
        }

        // layer 1
        #pragma unroll
        for (int nt = 0; nt < 4; ++nt) {
            f32x4 acc = {0.0f, 0.0f, 0.0f, 0.0f};
            #pragma unroll
            for (int kc = 0; kc < 4; ++kc) {
                const long fo = (long)((kc * 4 + nt) * 64 + lane) * 8;
                const half8 wh = *(const half8*)(w1h + fo);
                const half8 wl = *(const half8*)(w1l + fo);
                acc = MFMA16(a1h[kc], wh, acc);
                acc = MFMA16(a1l[kc], wh, acc);
                acc = MFMA16(a1h[kc], wl, acc);
            }
            #pragma unroll
            for (int r = 0; r < 4; ++r) {
                const float v = acc[r] + bb1[nt];
                hbuf[(row0 + r) * 68 + nt * 16 + m] = v > 0.0f ? v : 0.0f;
            }
        }

        // layer 2
        half8 a2h[2], a2l[2];
        #pragma unroll
        for (int kc = 0; kc < 2; ++kc) {
            const float4 va = *(const float4*)&hbuf[arow_l * 68 + kc * 32 + quad * 8];
            const float4 vb = *(const float4*)&hbuf[arow_l * 68 + kc * 32 + quad * 8 + 4];
            const float xs[8] = {va.x, va.y, va.z, va.w, vb.x, vb.y, vb.z, vb.w};
            split16(xs, a2h[kc], a2l[kc]);
        }
        #pragma unroll
        for (int nt = 0; nt < 4; ++nt) {
            f32x4 acc = {0.0f, 0.0f, 0.0f, 0.0f};
            #pragma unroll
            for (int kc = 0; kc < 2; ++kc) {
                const long fo = (long)((kc * 4 + nt) * 64 + lane) * 8;
                const half8 wh = *(const half8*)(w2h + fo);
                const half8 wl = *(const half8*)(w2l + fo);
                acc = MFMA16(a2h[kc], wh, acc);
                acc = MFMA16(a2l[kc], wh, acc);
                acc = MFMA16(a2h[kc], wl, acc);
            }
            #pragma unroll
            for (int r = 0; r < 4; ++r) {
                const float v = acc[r] + bb2[nt];
                hbuf[(row0 + r) * 68 + nt * 16 + m] = v > 0.0f ? v : 0.0f;
            }
        }

        // layer 3 -> x rows in hbuf (stay resident until kernel end)
        half8 a3h[2], a3l[2];
        #pragma unroll
        for (int kc = 0; kc < 2; ++kc) {
            const float4 va = *(const float4*)&hbuf[arow_l * 68 + kc * 32 + quad * 8];
            const float4 vb = *(const float4*)&hbuf[arow_l * 68 + kc * 32 + quad * 8 + 4];
            const float xs[8] = {va.x, va.y, va.z, va.w, vb.x, vb.y, vb.z, vb.w};
            split16(xs, a3h[kc], a3l[kc]);
        }
        #pragma unroll
        for (int nt = 0; nt < 4; ++nt) {
            f32x4 acc = {0.0f, 0.0f, 0.0f, 0.0f};
            #pragma unroll
            for (int kc = 0; kc < 2; ++kc) {
                const long fo = (long)((kc * 4 + nt) * 64 + lane) * 8;
                const half8 wh = *(const half8*)(w3h + fo);
                const half8 wl = *(const half8*)(w3l + fo);
                acc = MFMA16(a3h[kc], wh, acc);
                acc = MFMA16(a3l[kc], wh, acc);
                acc = MFMA16(a3h[kc], wl, acc);
            }
            #pragma unroll
            for (int r = 0; r < 4; ++r)
                hbuf[(row0 + r) * 68 + nt * 16 + m] = acc[r] + bb3[nt];
        }
    }

    // A-frags (wave-local hbuf rows): fp16 screen operands
    half8 a0h, a1h;
    {
        const float* xrow = &hbuf[(w * 16 + m) * 68];
        const float4 xa = *(const float4*)(xrow + quad * 8);
        const float4 xb = *(const float4*)(xrow + quad * 8 + 4);
        const float4 xc = *(const float4*)(xrow + 32 + quad * 8);
        const float4 xd = *(const float4*)(xrow + 32 + quad * 8 + 4);
        const float x0[8] = {xa.x, xa.y, xa.z, xa.w, xb.x, xb.y, xb.z, xb.w};
        const float x1[8] = {xc.x, xc.y, xc.z, xc.w, xd.x, xd.y, xd.z, xd.w};
        #pragma unroll
        for (int j = 0; j < 8; ++j) {
            a0h[j] = (_Float16)x0[j];
            a1h[j] = (_Float16)x1[j];
        }
    }
    __syncthreads();   // hbuf x final + e2s + cand_cnt/keys visible

    // ===== VQ scan: 128 tiles, wave-private ring, counted vmcnt, NO barriers
    float bd[4] = {3.4e38f, 3.4e38f, 3.4e38f, 3.4e38f};
    int   bi[4] = {0, 0, 0, 0};

    char* ring = stg[w][0];     // 3 x 2048 contiguous for this wave
    const long lofs = (long)lane * 8;

    // prologue: stage tiles 0,1 (2 gld16 each) -> outstanding = 4
    #pragma unroll
    for (int tl = 0; tl < 2; ++tl) {
        gld16(ring + tl * 2048,        cbhp + (long)tl * 1024 + lofs);
        gld16(ring + tl * 2048 + 1024, cbhp + (long)tl * 1024 + 512 + lofs);
    }

    for (int tile = 0; tile < 128; ++tile) {
        // stage tile+2 into ring slot (tile+2)%3 (src clamped; dup harmless)
        {
            const int nt = (tile + 2 < 128) ? tile + 2 : 127;
            char* dst = ring + ((tile + 2) % 3) * 2048;
            gld16(dst,        cbhp + (long)nt * 1024 + lofs);
            gld16(dst + 1024, cbhp + (long)nt * 1024 + 512 + lofs);
        }
        // wait: tile's own 2 loads retired (FIFO: oldest first), 4 in flight
        asm volatile("s_waitcnt vmcnt(4)" ::: "memory");
        __builtin_amdgcn_sched_barrier(0);

        const char* bufp = ring + (tile % 3) * 2048;
        const half8 th0 = *(const half8*)(bufp + lane * 16);
        const half8 th1 = *(const half8*)(bufp + 1024 + lane * 16);
        const float e2v = e2s[tile * 16 + m];
        f32x4 acc = {0.0f, 0.0f, 0.0f, 0.0f};
        __builtin_amdgcn_s_setprio(1);
        acc = MFMA16(a0h, th0, acc);
        acc = MFMA16(a1h, th1, acc);
        __builtin_amdgcn_s_setprio(0);

        const int code = tile * 16 + m;
        bool pushm[4]; int pip[4];
        #pragma unroll
        for (int r = 0; r < 4; ++r) {
            const float d = fmaf(-2.0f, acc[r], e2v);
            const bool lt = d < bd[r];
            // push loser iff within MARG of winner (== R3's two cases)
            pushm[r] = __builtin_fabsf(d - bd[r]) < MARG;
            pip[r] = lt ? bi[r] : code;
            bd[r] = lt ? d : bd[r];
            bi[r] = lt ? code : bi[r];
        }
        if (__any((int)(pushm[0] | pushm[1] | pushm[2] | pushm[3]))) {
            #pragma unroll
            for (int r = 0; r < 4; ++r) {
                if (pushm[r]) {
                    const int slot = atomicAdd(&cand_cnt, 1);
                    if (slot < CAND_CAP)
                        cand_pc[slot] = ((w * 16 + quad * 4 + r) << 16) | pip[r];
                }
            }
        }
    }

    // per-point screened winner via 16-lane argmin butterfly; near-tie pushes
    {
        float rd[4]; int ri[4];
        #pragma unroll
        for (int r = 0; r < 4; ++r) { rd[r] = bd[r]; ri[r] = bi[r]; }
        #pragma unroll
        for (int off = 1; off <= 8; off <<= 1) {
            #pragma unroll
            for (int r = 0; r < 4; ++r) {
                const float od = __shfl_xor(rd[r], off, 64);
                const int   oi = __shfl_xor(ri[r], off, 64);
                if (od < rd[r] || (od == rd[r] && oi < ri[r])) {
                    rd[r] = od; ri[r] = oi;
                }
            }
        }
        #pragma unroll
        for (int r = 0; r < 4; ++r) {
            const int pl = w * 16 + quad * 4 + r;
            if (m == 0) win_sh[pl] = ri[r];
            if (bd[r] <= rd[r] + MARG && bi[r] != ri[r]) {
                const int slot = atomicAdd(&cand_cnt, 1);
                if (slot < CAND_CAP)
                    cand_pc[slot] = (pl << 16) | bi[r];
            }
        }
    }
    __syncthreads();    // win_sh + cand list final (also drains stage loads)

    // exact fp32 rescore (x from LDS, cb rows from global/L2), atomicMin keys
    {
        if (t < BPTS) {
            const int n = win_sh[t];
            const float ex = exdist(&hbuf[t * 68], cb + (long)n * OUT_DIM, e2s[n]);
            atomicMin(&keys[t], packkey(ex, n));
        }
        const int L = min(cand_cnt, CAND_CAP);
        for (int l = t; l < L; l += NTHR) {
            const int pc = cand_pc[l];
            const int p = pc >> 16, n = pc & 0xFFFF;
            const float ex = exdist(&hbuf[p * 68], cb + (long)n * OUT_DIM, e2s[n]);
            atomicMin(&keys[p], packkey(ex, n));
        }
    }
    __syncthreads();

    if (t < BPTS) {
        const int code = (int)(keys[t] & 0xFFFFFFFFu);
        idx_sh[t] = code;
        idx_out[base + t] = (float)code;
    }
    __syncthreads();

    // gather q, write msg (only write), accumulate loss (x from LDS)
    float lsum = 0.0f;
    float4* mg = (float4*)(msg + base * OUT_DIM);
    #pragma unroll
    for (int mm = 0; mm < 4; ++mm) {
        const int v = t + NTHR * mm;
        const int p = v >> 4, k4 = v & 15;
        const int code = idx_sh[p];
        const float4 q = ((const float4*)(cb + (long)code * OUT_DIM))[k4];
        const float4 xv = *(const float4*)&hbuf[p * 68 + k4 * 4];
        const float dx = q.x - xv.x, dy = q.y - xv.y;
        const float dz = q.z - xv.z, dw2 = q.w - xv.w;
        lsum += dx * dx + dy * dy + dz * dz + dw2 * dw2;
        mg[v] = q;
    }
    #pragma unroll
    for (int off = 32; off > 0; off >>= 1) lsum += __shfl_down(lsum, off, 64);
    if (lane == 0) wred[w] = lsum;
    __syncthreads();
    if (t == 0) {
        float s = 0.0f;
        #pragma unroll
        for (int i = 0; i < NTHR / 64; ++i) s += wred[i];
        atomicAdd(loss_out, s * LOSS_SCALE);
    }
}

extern "C" void kernel_launch(void* const* d_in, const int* in_sizes, int n_in,
                              void* d_out, int out_size, void* d_ws, size_t ws_size,
                              hipStream_t stream) {
    const float* obs = (const float*)d_in[0];
    const float* W1  = (const float*)d_in[1];
    const float* b1  = (const float*)d_in[2];
    const float* W2  = (const float*)d_in[3];
    const float* b2  = (const float*)d_in[4];
    const float* W3  = (const float*)d_in[5];
    const float* b3  = (const float*)d_in[6];
    const float* cb  = (const float*)d_in[7];

    float* out  = (float*)d_out;
    float* msg  = out;
    float* idxf = out + MSG_ELEMS;
    float* loss = out + MSG_ELEMS + NPTS;

    char* ws = (char*)d_ws;
    float*     e2  = (float*)ws;                          // 8 KB
    _Float16*  cbh = (_Float16*)(ws + 8192);              // 256 KB (fp16)
    _Float16* w1h = (_Float16*)(ws + 532480);             // 16 KB
    _Float16* w1l = (_Float16*)(ws + 548864);             // 16 KB
    _Float16* w2h = (_Float16*)(ws + 565248);             // 8 KB
    _Float16* w2l = (_Float16*)(ws + 573440);             // 8 KB
    _Float16* w3h = (_Float16*)(ws + 581632);             // 8 KB
    _Float16* w3l = (_Float16*)(ws + 589824);             // 8 KB

    prep_all<<<80, 256, 0, stream>>>(cb, W1, W2, W3, e2, cbh,
                                     w1h, w1l, w2h, w2l, w3h, w3l, loss);
    fused_mlp_vq<<<NPTS / BPTS, NTHR, 0, stream>>>(
        obs, b1, b2, b3, w1h, w1l, w2h, w2l, w3h, w3l,
        cb, cbh, e2, msg, idxf, loss);
}

// Round 11
// 157.005 us; speedup vs baseline: 1.4200x; 1.4200x over previous
//
#include <hip/hip_runtime.h>

// VQSpeaker: obs[32,2048,128] -> 3-layer MLP -> x[65536,64] -> VQ argmin over
// codebook[2048,64] -> (msg = codebook[idx], idx, cmt_loss).
//
// Round 19: R17 base (best: fused 82us) + phase-interior reorder.
//   R18 (wave-private vmcnt rings) regressed 82->147: order-pinning + 4x
//   staging + occupancy drop. Reverted.
//   R17's stall theory: per-tile screen's conditional LDS stores (cand_pc)
//   alias-block hoisting of the next tile's stg ds_reads -> serial
//   read->MFMA->screen chains. Fix: per phase, ALL loads first (16 ds_read
//   + 8 e2), then 16 independent MFMAs (setprio), then 8 screens last.
//   Pure scheduling change; outputs bit-identical to R17.
//
// d_out layout (float32): msg[4194304] | idx[65536] (as float) | loss[1]
// d_ws: e2[2048] | cbh fp16 256KB | w1h/w1l 16KB ea | w2h/w2l/w3h/w3l 8KB ea

#define NPTS    65536
#define IN_DIM  128
#define HID     64
#define OUT_DIM 64
#define CB_N    2048
#define MSG_ELEMS (NPTS * OUT_DIM)
#define LOSS_SCALE (1.0f / 4194304.0f)
#define MARG 0.5f          // R3-proven screening margin
#define CAND_CAP 1024      // 8 per point
#define BPTS 128           // points per block (8 waves x 16)
#define NTHR 512

typedef __attribute__((ext_vector_type(8))) short short8;
typedef _Float16 half8 __attribute__((ext_vector_type(8)));
typedef __attribute__((ext_vector_type(4))) float f32x4;
typedef unsigned int u32;
typedef unsigned long long u64;

// async global->LDS, 16B/lane: LDS dest = wave-uniform base + lane*16
__device__ __forceinline__ void gld16(void* lds_base, const void* gsrc) {
    __builtin_amdgcn_global_load_lds(
        (const __attribute__((address_space(1))) u32*)gsrc,
        (__attribute__((address_space(3))) u32*)lds_base, 16, 0, 0);
}

// ---- merged prep, 80 blocks: 0-63 prep_cb, 64-71 prep_w, 72-79 e2(+loss) --
__global__ __launch_bounds__(256) void prep_all(
    const float* __restrict__ cb,
    const float* __restrict__ W1, const float* __restrict__ W2,
    const float* __restrict__ W3,
    float* __restrict__ e2,
    _Float16* __restrict__ cbh,
    _Float16* __restrict__ w1h, _Float16* __restrict__ w1l,
    _Float16* __restrict__ w2h, _Float16* __restrict__ w2l,
    _Float16* __restrict__ w3h, _Float16* __restrict__ w3l,
    float* __restrict__ loss)
{
    const int b = blockIdx.x, tid = threadIdx.x;
    if (b < 64) {
        // ---- prep_cb: one (code n, half h, quad) per thread ----
        const int id = b * 256 + tid;               // 0..16383
        const int n = id >> 3, h = (id >> 2) & 1, quad = id & 3;
        const int t = n >> 4, l15 = n & 15;
        const float* src = cb + (long)n * OUT_DIM + h * 32 + quad * 8;
        half8 hi;
        #pragma unroll
        for (int j = 0; j < 8; ++j)
            hi[j] = (_Float16)src[j];
        const long dst = ((long)(t * 2 + h) * 64 + quad * 16 + l15) * 8;
        *(half8*)(cbh + dst) = hi;
    } else if (b < 72) {
        // ---- prep_w: W1/W2/W3 -> MFMA B-frag order, fp16 hi/lo split ----
        const int id = (b - 64) * 256 + tid;        // 0..2047
        const int lane = id & 63;
        const int m = lane & 15, quad = lane >> 4;
        const float* W; _Float16 *dh, *dl; int frag;
        if (id < 1024)      { W = W1; dh = w1h; dl = w1l; frag = id >> 6; }
        else if (id < 1536) { W = W2; dh = w2h; dl = w2l; frag = (id - 1024) >> 6; }
        else                { W = W3; dh = w3h; dl = w3l; frag = (id - 1536) >> 6; }
        const int kc = frag >> 2, nt = frag & 3;
        half8 hi, lo;
        #pragma unroll
        for (int j = 0; j < 8; ++j) {
            const float v = W[(long)(kc * 32 + quad * 8 + j) * 64 + nt * 16 + m];
            hi[j] = (_Float16)v;
            lo[j] = (_Float16)(v - (float)hi[j]);
        }
        const long dst = (long)(frag * 64 + lane) * 8;
        *(half8*)(dh + dst) = hi;
        *(half8*)(dl + dst) = lo;
    } else {
        // ---- e2 + zero_loss ----
        if (b == 72 && tid == 0) *loss = 0.0f;
        const int c = (b - 72) * 256 + tid;
        const float4* row = (const float4*)(cb + (long)c * OUT_DIM);
        float s = 0.0f;
        #pragma unroll
        for (int mq = 0; mq < 16; ++mq) {
            const float4 v = row[mq];
            s += v.x * v.x + v.y * v.y + v.z * v.z + v.w * v.w;
        }
        e2[c] = s;
    }
}

#define MFMA16(A, B, C) __builtin_amdgcn_mfma_f32_16x16x32_f16(A, B, C, 0, 0, 0)

__device__ __forceinline__ void split16(const float* xs, half8& h, half8& l) {
    #pragma unroll
    for (int j = 0; j < 8; ++j) {
        h[j] = (_Float16)xs[j];
        l[j] = (_Float16)(xs[j] - (float)h[j]);
    }
}

// packed rescore key: (total-order fp32 dist << 32) | code.
// min over keys == (min dist, tie -> min code) == reference argmin semantics.
__device__ __forceinline__ u64 packkey(float d, int n) {
    u32 ub = __float_as_uint(d);
    ub = (ub & 0x80000000u) ? ~ub : (ub | 0x80000000u);
    return ((u64)ub << 32) | (u32)n;
}

// exact fp32 distance (R2/R3-proven pairing); xr is LDS, cbrow global.
__device__ __forceinline__ float exdist(
    const float* xr, const float* __restrict__ cbrow, float e2v)
{
    const float4* xp = (const float4*)xr;
    const float4* cp = (const float4*)cbrow;
    float a0 = 0.0f, a1 = 0.0f;
    #pragma unroll
    for (int mq = 0; mq < 16; ++mq) {
        const float4 xv = xp[mq], cv = cp[mq];
        a0 = fmaf(xv.x, cv.x, a0); a1 = fmaf(xv.y, cv.y, a1);
        a0 = fmaf(xv.z, cv.z, a0); a1 = fmaf(xv.w, cv.w, a1);
    }
    return fmaf(-2.0f, a0 + a1, e2v);
}

// ---------------- FUSED: MLP + VQ, x LDS-resident end-to-end ---------------
__global__ __launch_bounds__(NTHR, 4) void fused_mlp_vq(
    const float* __restrict__ obs,
    const float* __restrict__ b1, const float* __restrict__ b2,
    const float* __restrict__ b3,
    const _Float16* __restrict__ w1h, const _Float16* __restrict__ w1l,
    const _Float16* __restrict__ w2h, const _Float16* __restrict__ w2l,
    const _Float16* __restrict__ w3h, const _Float16* __restrict__ w3l,
    const float* __restrict__ cb,
    const _Float16* __restrict__ cbhp,
    const float* __restrict__ e2,
    float* __restrict__ msg,        // out only: quantize
    float* __restrict__ idx_out,
    float* __restrict__ loss_out)
{
    __shared__ float hbuf[BPTS * 68];       // 34.8 KB: mlp scratch then x
    __shared__ __align__(16) char stg[2][16384];  // 32 KB stage double buffer
    __shared__ int   cand_pc[CAND_CAP];     // 4 KB: (p_local<<16) | code
    __shared__ u64   keys[BPTS];            // packed rescore keys
    __shared__ int   win_sh[BPTS];          // screened winners
    __shared__ int   idx_sh[BPTS];
    __shared__ float wred[NTHR / 64];
    __shared__ int   cand_cnt;

    const int t = threadIdx.x, lane = t & 63, w = t >> 6;
    const int m = lane & 15, quad = lane >> 4;
    const long base = (long)blockIdx.x * BPTS;
    const int row0 = w * 16 + quad * 4;         // C-layout write rows (+r)
    const int arow_l = w * 16 + m;              // A-layout read row

    if (t == 0) cand_cnt = 0;
    if (t < BPTS) keys[t] = ~0ULL;

    // ================= MLP phase (R13-verbatim, wave-local, 8 waves) ========
    {
        float bb1[4], bb2[4], bb3[4];
        #pragma unroll
        for (int nt = 0; nt < 4; ++nt) {
            bb1[nt] = b1[nt * 16 + m];
            bb2[nt] = b2[nt * 16 + m];
            bb3[nt] = b3[nt * 16 + m];
        }

        const float* arow = obs + (base + w * 16 + m) * IN_DIM;
        half8 a1h[4], a1l[4];
        #pragma unroll
        for (int kc = 0; kc < 4; ++kc) {
            const float4 va = *(const float4*)(arow + kc * 32 + quad * 8);
            const float4 vb = *(const float4*)(arow + kc * 32 + quad * 8 + 4);
            const float xs[8] = {va.x, va.y, va.z, va.w, vb.x, vb.y, vb.z, vb.w};
            split16(xs, a1h[kc], a1l[kc]);
        }

        // layer 1
        #pragma unroll
        for (int nt = 0; nt < 4; ++nt) {
            f32x4 acc = {0.0f, 0.0f, 0.0f, 0.0f};
            #pragma unroll
            for (int kc = 0; kc < 4; ++kc) {
                const long fo = (long)((kc * 4 + nt) * 64 + lane) * 8;
                const half8 wh = *(const half8*)(w1h + fo);
                const half8 wl = *(const half8*)(w1l + fo);
                acc = MFMA16(a1h[kc], wh, acc);
                acc = MFMA16(a1l[kc], wh, acc);
                acc = MFMA16(a1h[kc], wl, acc);
            }
            #pragma unroll
            for (int r = 0; r < 4; ++r) {
                const float v = acc[r] + bb1[nt];
                hbuf[(row0 + r) * 68 + nt * 16 + m] = v > 0.0f ? v : 0.0f;
            }
        }

        // layer 2
        half8 a2h[2], a2l[2];
        #pragma unroll
        for (int kc = 0; kc < 2; ++kc) {
            const float4 va = *(const float4*)&hbuf[arow_l * 68 + kc * 32 + quad * 8];
            const float4 vb = *(const float4*)&hbuf[arow_l * 68 + kc * 32 + quad * 8 + 4];
            const float xs[8] = {va.x, va.y, va.z, va.w, vb.x, vb.y, vb.z, vb.w};
            split16(xs, a2h[kc], a2l[kc]);
        }
        #pragma unroll
        for (int nt = 0; nt < 4; ++nt) {
            f32x4 acc = {0.0f, 0.0f, 0.0f, 0.0f};
            #pragma unroll
            for (int kc = 0; kc < 2; ++kc) {
                const long fo = (long)((kc * 4 + nt) * 64 + lane) * 8;
                const half8 wh = *(const half8*)(w2h + fo);
                const half8 wl = *(const half8*)(w2l + fo);
                acc = MFMA16(a2h[kc], wh, acc);
                acc = MFMA16(a2l[kc], wh, acc);
                acc = MFMA16(a2h[kc], wl, acc);
            }
            #pragma unroll
            for (int r = 0; r < 4; ++r) {
                const float v = acc[r] + bb2[nt];
                hbuf[(row0 + r) * 68 + nt * 16 + m] = v > 0.0f ? v : 0.0f;
            }
        }

        // layer 3 -> x rows in hbuf (stay resident until kernel end)
        half8 a3h[2], a3l[2];
        #pragma unroll
        for (int kc = 0; kc < 2; ++kc) {
            const float4 va = *(const float4*)&hbuf[arow_l * 68 + kc * 32 + quad * 8];
            const float4 vb = *(const float4*)&hbuf[arow_l * 68 + kc * 32 + quad * 8 + 4];
            const float xs[8] = {va.x, va.y, va.z, va.w, vb.x, vb.y, vb.z, vb.w};
            split16(xs, a3h[kc], a3l[kc]);
        }
        #pragma unroll
        for (int nt = 0; nt < 4; ++nt) {
            f32x4 acc = {0.0f, 0.0f, 0.0f, 0.0f};
            #pragma unroll
            for (int kc = 0; kc < 2; ++kc) {
                const long fo = (long)((kc * 4 + nt) * 64 + lane) * 8;
                const half8 wh = *(const half8*)(w3h + fo);
                const half8 wl = *(const half8*)(w3l + fo);
                acc = MFMA16(a3h[kc], wh, acc);
                acc = MFMA16(a3l[kc], wh, acc);
                acc = MFMA16(a3h[kc], wl, acc);
            }
            #pragma unroll
            for (int r = 0; r < 4; ++r)
                hbuf[(row0 + r) * 68 + nt * 16 + m] = acc[r] + bb3[nt];
        }
    }

    // A-frags (wave-local hbuf rows): fp16 screen operands
    half8 a0h, a1h;
    {
        const float* xrow = &hbuf[(w * 16 + m) * 68];
        const float4 xa = *(const float4*)(xrow + quad * 8);
        const float4 xb = *(const float4*)(xrow + quad * 8 + 4);
        const float4 xc = *(const float4*)(xrow + 32 + quad * 8);
        const float4 xd = *(const float4*)(xrow + 32 + quad * 8 + 4);
        const float x0[8] = {xa.x, xa.y, xa.z, xa.w, xb.x, xb.y, xb.z, xb.w};
        const float x1[8] = {xc.x, xc.y, xc.z, xc.w, xd.x, xd.y, xd.z, xd.w};
        #pragma unroll
        for (int j = 0; j < 8; ++j) {
            a0h[j] = (_Float16)x0[j];
            a1h[j] = (_Float16)x1[j];
        }
    }

    // prologue: stage phase 0 (tiles 0-7, 16 KB) into buf0; 2 gld16 per wave
    #pragma unroll
    for (int j = 0; j < 2; ++j)
        gld16(stg[0] + (w * 2 + j) * 1024,
              cbhp + (w * 2 + j) * 512 + lane * 8);
    __syncthreads();   // drains stage-0; hbuf + cand_cnt + keys visible

    // ========== VQ scan: 16 phases x 8 tiles; loads-first phase interior ====
    float bd[4] = {3.4e38f, 3.4e38f, 3.4e38f, 3.4e38f};
    int   bi[4] = {0, 0, 0, 0};

    for (int ph = 0; ph < 16; ++ph) {
        if (ph < 15) {      // stage next chunk into the other buffer
            const _Float16* cbq = cbhp + (long)(ph + 1) * 8192;
            #pragma unroll
            for (int j = 0; j < 2; ++j)
                gld16(stg[(ph + 1) & 1] + (w * 2 + j) * 1024,
                      cbq + (w * 2 + j) * 512 + lane * 8);
        }
        const char* bufp = stg[ph & 1];

        // ---- ALL memory ops for the phase first (no cand stores yet) ----
        half8 th[16];
        float e2v[8];
        #pragma unroll
        for (int tl = 0; tl < 8; ++tl) {
            th[tl * 2]     = *(const half8*)(bufp + tl * 2048 + lane * 16);
            th[tl * 2 + 1] = *(const half8*)(bufp + tl * 2048 + 1024 + lane * 16);
            e2v[tl] = e2[(ph * 8 + tl) * 16 + m];
        }

        // ---- 16 MFMAs: 8 independent 2-chains ----
        f32x4 acc[8];
        __builtin_amdgcn_s_setprio(1);
        #pragma unroll
        for (int tl = 0; tl < 8; ++tl) {
            f32x4 z = {0.0f, 0.0f, 0.0f, 0.0f};
            z = MFMA16(a0h, th[tl * 2], z);
            z = MFMA16(a1h, th[tl * 2 + 1], z);
            acc[tl] = z;
        }
        __builtin_amdgcn_s_setprio(0);

        // ---- 8 screens (pure VALU + rare wave-uniform push path) ----
        #pragma unroll
        for (int tl = 0; tl < 8; ++tl) {
            const int g = ph * 8 + tl;
            const int code = g * 16 + m;
            bool pushm[4]; int pip[4];
            #pragma unroll
            for (int r = 0; r < 4; ++r) {
                const float d = fmaf(-2.0f, acc[tl][r], e2v[tl]);
                const bool lt = d < bd[r];
                // push loser iff within MARG of winner (== R3's two cases)
                pushm[r] = __builtin_fabsf(d - bd[r]) < MARG;
                pip[r] = lt ? bi[r] : code;
                bd[r] = lt ? d : bd[r];
                bi[r] = lt ? code : bi[r];
            }
            if (__any((int)(pushm[0] | pushm[1] | pushm[2] | pushm[3]))) {
                #pragma unroll
                for (int r = 0; r < 4; ++r) {
                    if (pushm[r]) {
                        const int slot = atomicAdd(&cand_cnt, 1);
                        if (slot < CAND_CAP)
                            cand_pc[slot] = ((w * 16 + quad * 4 + r) << 16) | pip[r];
                    }
                }
            }
        }
        __syncthreads();    // scan of buf done; next-phase stage drained
    }

    // per-point screened winner via 16-lane argmin butterfly; near-tie pushes
    {
        float rd[4]; int ri[4];
        #pragma unroll
        for (int r = 0; r < 4; ++r) { rd[r] = bd[r]; ri[r] = bi[r]; }
        #pragma unroll
        for (int off = 1; off <= 8; off <<= 1) {
            #pragma unroll
            for (int r = 0; r < 4; ++r) {
                const float od = __shfl_xor(rd[r], off, 64);
                const int   oi = __shfl_xor(ri[r], off, 64);
                if (od < rd[r] || (od == rd[r] && oi < ri[r])) {
                    rd[r] = od; ri[r] = oi;
                }
            }
        }
        #pragma unroll
        for (int r = 0; r < 4; ++r) {
            const int pl = w * 16 + quad * 4 + r;
            if (m == 0) win_sh[pl] = ri[r];
            if (bd[r] <= rd[r] + MARG && bi[r] != ri[r]) {
                const int slot = atomicAdd(&cand_cnt, 1);
                if (slot < CAND_CAP)
                    cand_pc[slot] = (pl << 16) | bi[r];
            }
        }
    }
    __syncthreads();    // win_sh + cand list final

    // exact fp32 rescore (x from LDS, cb rows from global/L2), atomicMin keys
    {
        if (t < BPTS) {
            const int n = win_sh[t];
            const float ex = exdist(&hbuf[t * 68], cb + (long)n * OUT_DIM, e2[n]);
            atomicMin(&keys[t], packkey(ex, n));
        }
        const int L = min(cand_cnt, CAND_CAP);
        for (int l = t; l < L; l += NTHR) {
            const int pc = cand_pc[l];
            const int p = pc >> 16, n = pc & 0xFFFF;
            const float ex = exdist(&hbuf[p * 68], cb + (long)n * OUT_DIM, e2[n]);
            atomicMin(&keys[p], packkey(ex, n));
        }
    }
    __syncthreads();

    if (t < BPTS) {
        const int code = (int)(keys[t] & 0xFFFFFFFFu);
        idx_sh[t] = code;
        idx_out[base + t] = (float)code;
    }
    __syncthreads();

    // gather q, write msg (only write), accumulate loss (x from LDS)
    float lsum = 0.0f;
    float4* mg = (float4*)(msg + base * OUT_DIM);
    #pragma unroll
    for (int mm = 0; mm < 4; ++mm) {
        const int v = t + NTHR * mm;
        const int p = v >> 4, k4 = v & 15;
        const int code = idx_sh[p];
        const float4 q = ((const float4*)(cb + (long)code * OUT_DIM))[k4];
        const float4 xv = *(const float4*)&hbuf[p * 68 + k4 * 4];
        const float dx = q.x - xv.x, dy = q.y - xv.y;
        const float dz = q.z - xv.z, dw2 = q.w - xv.w;
        lsum += dx * dx + dy * dy + dz * dz + dw2 * dw2;
        mg[v] = q;
    }
    #pragma unroll
    for (int off = 32; off > 0; off >>= 1) lsum += __shfl_down(lsum, off, 64);
    if (lane == 0) wred[w] = lsum;
    __syncthreads();
    if (t == 0) {
        float s = 0.0f;
        #pragma unroll
        for (int i = 0; i < NTHR / 64; ++i) s += wred[i];
        atomicAdd(loss_out, s * LOSS_SCALE);
    }
}

extern "C" void kernel_launch(void* const* d_in, const int* in_sizes, int n_in,
                              void* d_out, int out_size, void* d_ws, size_t ws_size,
                              hipStream_t stream) {
    const float* obs = (const float*)d_in[0];
    const float* W1  = (const float*)d_in[1];
    const float* b1  = (const float*)d_in[2];
    const float* W2  = (const float*)d_in[3];
    const float* b2  = (const float*)d_in[4];
    const float* W3  = (const float*)d_in[5];
    const float* b3  = (const float*)d_in[6];
    const float* cb  = (const float*)d_in[7];

    float* out  = (float*)d_out;
    float* msg  = out;
    float* idxf = out + MSG_ELEMS;
    float* loss = out + MSG_ELEMS + NPTS;

    char* ws = (char*)d_ws;
    float*     e2  = (float*)ws;                          // 8 KB
    _Float16*  cbh = (_Float16*)(ws + 8192);              // 256 KB (fp16)
    _Float16* w1h = (_Float16*)(ws + 532480);             // 16 KB
    _Float16* w1l = (_Float16*)(ws + 548864);             // 16 KB
    _Float16* w2h = (_Float16*)(ws + 565248);             // 8 KB
    _Float16* w2l = (_Float16*)(ws + 573440);             // 8 KB
    _Float16* w3h = (_Float16*)(ws + 581632);             // 8 KB
    _Float16* w3l = (_Float16*)(ws + 589824);             // 8 KB

    prep_all<<<80, 256, 0, stream>>>(cb, W1, W2, W3, e2, cbh,
                                     w1h, w1l, w2h, w2l, w3h, w3l, loss);
    fused_mlp_vq<<<NPTS / BPTS, NTHR, 0, stream>>>(
        obs, b1, b2, b3, w1h, w1l, w2h, w2l, w3h, w3l,
        cb, cbh, e2, msg, idxf, loss);
}